// Round 4
// baseline (998.883 us; speedup 1.0000x reference)
//
#include <hip/hip_runtime.h>

#define Vn 200000
#define PADI 199999
#define NBLK 448

typedef unsigned short ushort_t;
typedef unsigned int uint_t;
typedef __attribute__((ext_vector_type(8))) short short8;
typedef __attribute__((ext_vector_type(4))) float float4v;

__device__ __forceinline__ float sigm(float x) { return 1.f / (1.f + expf(-x)); }
__device__ __forceinline__ float dot4(float4 a, float4 b) {
  return a.x*b.x + a.y*b.y + a.z*b.z + a.w*b.w;
}
__device__ __forceinline__ ushort_t f2bf(float x) {
  uint_t u = __float_as_uint(x);
  uint_t r = (u + 0x7fffu + ((u >> 16) & 1u)) >> 16;
  return (ushort_t)r;
}
__device__ __forceinline__ float bf2f(ushort_t h) { return __uint_as_float(((uint_t)h) << 16); }

__device__ __forceinline__ float2 block_reduce2(float a, float b, float2* red) {
  #pragma unroll
  for (int off = 32; off; off >>= 1) { a += __shfl_down(a, off); b += __shfl_down(b, off); }
  __syncthreads();
  if ((threadIdx.x & 63) == 0) red[threadIdx.x >> 6] = make_float2(a, b);
  __syncthreads();
  float2 r;
  r.x = red[0].x + red[1].x + red[2].x + red[3].x;
  r.y = red[0].y + red[1].y + red[2].y + red[3].y;
  return r;
}

// device-scope grid barrier: monotonic phase counter, cnt zeroed by prep each call
__device__ __forceinline__ void grid_bar(unsigned* cnt, int& phase) {
  __syncthreads();
  if (threadIdx.x == 0) {
    phase++;
    __threadfence();
    __hip_atomic_fetch_add(cnt, 1u, __ATOMIC_RELEASE, __HIP_MEMORY_SCOPE_AGENT);
    while (__hip_atomic_load(cnt, __ATOMIC_RELAXED, __HIP_MEMORY_SCOPE_AGENT) <
           (unsigned)(NBLK * phase))
      __builtin_amdgcn_s_sleep(2);
    __threadfence();
  }
  __syncthreads();
}

// ---------------------------------------------------------------- prep: all weight reshapes in one launch
__global__ __launch_bounds__(256) void prep_kernel(
    const float* __restrict__ sew1, const float* __restrict__ sew2,
    const float* __restrict__ Wih, const float* __restrict__ Whh,
    const float* __restrict__ bih, const float* __restrict__ bhh,
    float* __restrict__ w1t, float* __restrict__ w2t,
    ushort_t* __restrict__ B2ih, ushort_t* __restrict__ B2hh,
    float* __restrict__ bias_s, unsigned* __restrict__ bar) {
  int b = blockIdx.x, t = threadIdx.x;
  if (b < 512) {                    // w1t[k*512+u] = sew1[u*256+k]
    int idx = b*256 + t;
    int c = idx >> 9, r = idx & 511;
    w1t[idx] = sew1[(size_t)r*256 + c];
  } else if (b < 1024) {            // w2t[u*256+t] = sew2[t*512+u]
    int idx = (b-512)*256 + t;
    int c = idx >> 8, r = idx & 255;
    w2t[idx] = sew2[(size_t)r*512 + c];
  } else if (b < 2816) {            // B2ih rows: [hi|hi|lo]
    int n = b - 1024;
    float v = Wih[(size_t)n*256 + t];
    ushort_t hi = f2bf(v), lo = f2bf(v - bf2f(hi));
    ushort_t* row = B2ih + (size_t)n*768;
    row[t] = hi; row[256+t] = hi; row[512+t] = lo;
  } else if (b < 4608) {            // B2hh rows from Whh[n][0:256]
    int n = b - 2816;
    float v = Whh[(size_t)n*512 + t];
    ushort_t hi = f2bf(v), lo = f2bf(v - bf2f(hi));
    ushort_t* row = B2hh + (size_t)n*768;
    row[t] = hi; row[256+t] = hi; row[512+t] = lo;
  } else if (b < 4615) {            // bias_s = bih + bhh (first 1792)
    int i = (b-4608)*256 + t;
    bias_s[i] = bih[i] + bhh[i];
  } else {                          // zero grid barrier
    if (t < 8) bar[t] = 0u;
  }
}

// ---------------------------------------------------------------- neighbor encoder
__global__ __launch_bounds__(256) void enc_kernel(
    const float* __restrict__ emb, const float* __restrict__ gcnW, const float* __restrict__ gcnb,
    const float* __restrict__ gateW, const float* __restrict__ gateb,
    const int* __restrict__ knn_tab,
    const int* __restrict__ query, const int* __restrict__ support,
    const int* __restrict__ qlc, const int* __restrict__ qrc,
    const int* __restrict__ slc, const int* __restrict__ src,
    float* __restrict__ xbuf) {   // 2056 x 256; support rows at 2048..2052
  __shared__ float center[128];
  __shared__ float simsu[192];    // 0..127 conn, 128..191 knn
  __shared__ int idr[128], ide[128];
  __shared__ int kidxs[64];
  __shared__ int sel[32], sel2[32];
  __shared__ int cnt1, cnt2;
  __shared__ float catbuf[256];
  __shared__ float knnA[128], knnB[128];
  __shared__ float part1[256], part2[256];
  __shared__ float structural[128], knnm[128];
  __shared__ float2 red2[4];

  int t = threadIdx.x;
  int g = blockIdx.x;
  int eid; const int* conn; float* outp;
  if (g < 2048)      { eid = query[2*g];                 conn = qlc + (size_t)g*256;      outp = xbuf + (size_t)g*256; }
  else if (g < 4096) { int b = g-2048; eid = query[2*b+1];  conn = qrc + (size_t)b*256;   outp = xbuf + (size_t)b*256 + 128; }
  else if (g < 4101) { int b = g-4096; eid = support[2*b];  conn = slc + (size_t)b*256;   outp = xbuf + (size_t)(2048+b)*256; }
  else               { int b = g-4101; eid = support[2*b+1]; conn = src + (size_t)b*256;  outp = xbuf + (size_t)(2048+b)*256 + 128; }
  if (eid < 0 || eid >= Vn) eid = PADI;

  if (t == 0) { cnt1 = 0; cnt2 = 0; }
  if (t < 128) {
    int2 cc = ((const int2*)conn)[t];
    idr[t] = cc.x; ide[t] = cc.y;
    center[t] = emb[(size_t)eid*128 + t];
  } else if (t < 192) {
    int kk = knn_tab[(size_t)eid*64 + (t-128)];
    kidxs[t-128] = (kk < 0 || kk >= Vn) ? PADI : kk;
  }
  __syncthreads();

  int gid = t >> 4, ll = t & 15;
  float4 cen0 = *(const float4*)&center[ll*8];
  float4 cen1 = *(const float4*)&center[ll*8 + 4];
  float cn2 = dot4(cen0, cen0) + dot4(cen1, cen1);
  #pragma unroll
  for (int off = 8; off; off >>= 1) cn2 += __shfl_down(cn2, off, 16);
  cn2 = __shfl(cn2, 0, 16);
  float cn = fmaxf(sqrtf(cn2), 1e-8f);

  // unified similarity loop: 3 rounds x 16 groups x 4 rows = 192 (conn 0..127, knn 128..191)
  #pragma unroll
  for (int it = 0; it < 3; ++it) {
    int rbase = it*64 + gid*4;
    int e[4];
    #pragma unroll
    for (int rr = 0; rr < 4; ++rr) {
      int n = rbase + rr;
      e[rr] = (n < 128) ? ide[n] : kidxs[n-128];
    }
    float d[4], m[4];
    #pragma unroll
    for (int rr = 0; rr < 4; ++rr) {
      const float4* p = (const float4*)(emb + (size_t)e[rr]*128);
      float4 a = p[ll*2], bb = p[ll*2+1];
      d[rr] = dot4(a, cen0) + dot4(bb, cen1);
      m[rr] = dot4(a, a) + dot4(bb, bb);
    }
    #pragma unroll
    for (int off = 8; off; off >>= 1) {
      #pragma unroll
      for (int rr = 0; rr < 4; ++rr) {
        d[rr] += __shfl_down(d[rr], off, 16);
        m[rr] += __shfl_down(m[rr], off, 16);
      }
    }
    if (ll == 0) {
      #pragma unroll
      for (int rr = 0; rr < 4; ++rr)
        simsu[rbase+rr] = d[rr] / (cn * fmaxf(sqrtf(m[rr]), 1e-8f));
    }
  }
  __syncthreads();

  // top-32 selections (rank count; jax.lax.top_k tie-break: lower index wins)
  if (t < 128) {
    float my = simsu[t];
    int c = 0;
    for (int j = 0; j < 128; ++j) {
      float sj = simsu[j];
      c += (sj > my) || (sj == my && j < t);
    }
    if (c < 32) { int p = atomicAdd(&cnt1, 1); sel[p] = t; }
  } else if (t < 192) {
    int i = t - 128;
    float my = simsu[128 + i];
    int c = 0;
    for (int j = 0; j < 64; ++j) {
      float sj = simsu[128 + j];
      c += (sj > my) || (sj == my && j < i);
    }
    if (c < 32) { int p = atomicAdd(&cnt2, 1); sel2[p] = i; }
  }
  __syncthreads();

  {
    int i = t & 127;
    float a0 = 0.f, a1 = 0.f, a2 = 0.f, a3 = 0.f;
    float k0 = 0.f, k1 = 0.f;
    if (t < 128) {
      #pragma unroll 2
      for (int k = 0; k < 32; k += 4) {
        a0 += emb[(size_t)idr[sel[k+0]]*128 + i];
        a1 += emb[(size_t)idr[sel[k+1]]*128 + i];
        a2 += emb[(size_t)idr[sel[k+2]]*128 + i];
        a3 += emb[(size_t)idr[sel[k+3]]*128 + i];
      }
      catbuf[i] = (a0+a1+a2+a3) * (1.f/32.f);
      #pragma unroll 2
      for (int k = 0; k < 16; k += 2) {
        k0 += emb[(size_t)kidxs[sel2[k+0]]*128 + i];
        k1 += emb[(size_t)kidxs[sel2[k+1]]*128 + i];
      }
      knnA[i] = k0 + k1;
    } else {
      #pragma unroll 2
      for (int k = 0; k < 32; k += 4) {
        a0 += emb[(size_t)ide[sel[k+0]]*128 + i];
        a1 += emb[(size_t)ide[sel[k+1]]*128 + i];
        a2 += emb[(size_t)ide[sel[k+2]]*128 + i];
        a3 += emb[(size_t)ide[sel[k+3]]*128 + i];
      }
      catbuf[128 + i] = (a0+a1+a2+a3) * (1.f/32.f);
      #pragma unroll 2
      for (int k = 16; k < 32; k += 2) {
        k0 += emb[(size_t)kidxs[sel2[k+0]]*128 + i];
        k1 += emb[(size_t)kidxs[sel2[k+1]]*128 + i];
      }
      knnB[i] = k0 + k1;
    }
  }
  __syncthreads();

  {
    int i = t & 127, half = t >> 7;
    const float4* w1p = (const float4*)(gcnW + (size_t)i*256 + half*128);
    const float4* c1p = (const float4*)(catbuf + half*128);
    float p1 = 0.f;
    #pragma unroll 8
    for (int j = 0; j < 32; ++j) {
      float4 w = w1p[j], a = c1p[j];
      p1 += dot4(w, a);
    }
    const float4* w2p = (const float4*)(gcnW + (size_t)i*256 + 128 + half*64);
    const float4* kap = (const float4*)(knnA + half*64);
    const float4* kbp = (const float4*)(knnB + half*64);
    float p2 = 0.f;
    #pragma unroll 8
    for (int j = 0; j < 16; ++j) {
      float4 w = w2p[j], xa = kap[j], xb = kbp[j];
      float4 s = make_float4(xa.x+xb.x, xa.y+xb.y, xa.z+xb.z, xa.w+xb.w);
      p2 += dot4(w, s);
    }
    part1[t] = p1;
    part2[t] = p2 * (1.f/32.f);
  }
  __syncthreads();
  if (t < 128) {
    structural[t] = tanhf(part1[t] + part1[t+128] + gcnb[t]);
    knnm[t]       = tanhf(part2[t] + part2[t+128] + gcnb[t]);
  }
  __syncthreads();

  float gv = (t < 128) ? structural[t]*gateW[t] : knnm[t-128]*gateW[t];
  float2 rr = block_reduce2(gv, 0.f, red2);
  float alpha = sigm(rr.x + gateb[0]);
  if (t < 128) outp[t] = (1.f - alpha)*structural[t] + alpha*knnm[t];
}

// ---------------------------------------------------------------- fused persistent LSTM pipeline
// phases: qenc(2056 rows) -> bar -> [finalize b<7] gemm0 -> bar -> gate0 -> bar ->
//         s=1..3: gemm -> bar -> gate / gatecos
__device__ __forceinline__ void gemm_phase(
    const ushort_t* __restrict__ A2, const ushort_t* __restrict__ B2T,
    float* __restrict__ C, const float* __restrict__ addmat, const float* __restrict__ cv,
    int bx, int by, int t, char* smem) {
  ushort_t* As = (ushort_t*)smem;             // 128 x 40
  ushort_t* Bs = (ushort_t*)(smem + 10240);   // 64 x 40
  int m0 = by*128, n0 = bx*64;
  int wid = t >> 6, lane = t & 63;
  int wm = (wid >> 1) * 64, wn = (wid & 1) * 32;
  int q = lane >> 4, fr = lane & 15;
  float4v acc[4][2];
  #pragma unroll
  for (int i = 0; i < 4; ++i) { acc[i][0] = (float4v)0.f; acc[i][1] = (float4v)0.f; }

  int row = t >> 2, ch = t & 3;
  for (int k0 = 0; k0 < 768; k0 += 32) {
    *(short8*)&As[row*40 + ch*8]      = *(const short8*)(A2 + (size_t)(m0+row)*768 + k0 + ch*8);
    *(short8*)&As[(row+64)*40 + ch*8] = *(const short8*)(A2 + (size_t)(m0+row+64)*768 + k0 + ch*8);
    *(short8*)&Bs[row*40 + ch*8]      = *(const short8*)(B2T + (size_t)(n0+row)*768 + k0 + ch*8);
    __syncthreads();
    short8 af[4], bg[2];
    #pragma unroll
    for (int mt = 0; mt < 4; ++mt) af[mt] = *(const short8*)&As[(wm + mt*16 + fr)*40 + q*8];
    #pragma unroll
    for (int nt = 0; nt < 2; ++nt) bg[nt] = *(const short8*)&Bs[(wn + nt*16 + fr)*40 + q*8];
    #pragma unroll
    for (int mt = 0; mt < 4; ++mt)
      #pragma unroll
      for (int nt = 0; nt < 2; ++nt)
        acc[mt][nt] = __builtin_amdgcn_mfma_f32_16x16x32_bf16(af[mt], bg[nt], acc[mt][nt], 0, 0, 0);
    __syncthreads();
  }
  #pragma unroll
  for (int mt = 0; mt < 4; ++mt) {
    int gm = m0 + wm + mt*16 + q*4;
    #pragma unroll
    for (int nt = 0; nt < 2; ++nt) {
      int gn = n0 + wn + nt*16 + fr;
      float cvv = cv ? cv[gn] : 0.f;
      #pragma unroll
      for (int reg = 0; reg < 4; ++reg) {
        size_t off = (size_t)(gm + reg) * 1792 + gn;
        float x = acc[mt][nt][reg] + cvv;
        if (addmat) x += addmat[off];
        C[off] = x;
      }
    }
  }
}

__device__ __forceinline__ void gate_phase(
    const float* __restrict__ Z, const float* __restrict__ qg,
    float* __restrict__ c, ushort_t* __restrict__ a2, int step0, int b, int t) {
  for (int idx = b*256 + t; idx < 2048*512; idx += NBLK*256) {
    int r = idx >> 9, j = idx & 511;
    const float* zr = Z + (size_t)r * 1792;
    float zi = zr[j], zf = zr[512 + j], zg = zr[1024 + j];
    float cold = step0 ? 0.f : c[idx];
    float c2 = sigm(zf) * cold + sigm(zi) * tanhf(zg);
    c[idx] = c2;
    if (j < 256) {
      float zo = zr[1536 + j];
      float h = qg[(size_t)r*256 + j] + sigm(zo) * tanhf(c2);
      ushort_t hi = f2bf(h), lo = f2bf(h - bf2f(hi));
      ushort_t* row = a2 + (size_t)r*768;
      row[j] = hi; row[256 + j] = lo; row[512 + j] = hi;
    }
  }
}

__global__ __launch_bounds__(256, 2) void lstm_kernel(
    const float* __restrict__ xbuf, const float* __restrict__ w1t, const float* __restrict__ b1,
    const float* __restrict__ w2t, const float* __restrict__ b2,
    const float* __restrict__ lng, const float* __restrict__ lnb,
    const float* __restrict__ whh_full,
    const ushort_t* __restrict__ B2ih, const ushort_t* __restrict__ B2hh,
    const float* __restrict__ bias_s,
    float* __restrict__ qg, ushort_t* __restrict__ A2,
    float* __restrict__ z_supp, float* __restrict__ sg_hat,
    float* __restrict__ Abuf, float* __restrict__ Zbuf, float* __restrict__ cbuf,
    float* __restrict__ outv, unsigned* __restrict__ bar) {
  __shared__ __align__(16) char smem[24640];
  int t = threadIdx.x;
  int b = blockIdx.x;
  int phase = 0;

  // ---- phase 1: qenc (MLP+LN) on 2056 rows, 8 rows/block, emits A2 for rows<2048
  if (b < 257) {
    float (*xs)[256]  = (float (*)[256])smem;
    float (*hsm)[512] = (float (*)[512])(smem + 8192);
    float2* red2 = (float2*)(smem + 8192 + 16384);
    int r0 = b * 8;
    #pragma unroll
    for (int rr = 0; rr < 8; ++rr) xs[rr][t] = xbuf[(size_t)(r0+rr)*256 + t];
    __syncthreads();
    #pragma unroll
    for (int uo = 0; uo < 512; uo += 256) {
      int u = uo + t;
      float bv = b1[u];
      float acc[8];
      #pragma unroll
      for (int rr = 0; rr < 8; ++rr) acc[rr] = bv;
      for (int j4 = 0; j4 < 64; ++j4) {
        float w0 = w1t[(size_t)(j4*4+0)*512 + u];
        float w1v = w1t[(size_t)(j4*4+1)*512 + u];
        float w2v = w1t[(size_t)(j4*4+2)*512 + u];
        float w3 = w1t[(size_t)(j4*4+3)*512 + u];
        #pragma unroll
        for (int rr = 0; rr < 8; ++rr) {
          float4 x = *(const float4*)&xs[rr][j4*4];
          acc[rr] += x.x*w0 + x.y*w1v + x.z*w2v + x.w*w3;
        }
      }
      #pragma unroll
      for (int rr = 0; rr < 8; ++rr) hsm[rr][u] = fmaxf(acc[rr], 0.f);
    }
    __syncthreads();
    float val[8];
    {
      float bv = b2[t];
      #pragma unroll
      for (int rr = 0; rr < 8; ++rr) val[rr] = bv + xs[rr][t];
      for (int u4 = 0; u4 < 128; ++u4) {
        float w0 = w2t[(size_t)(u4*4+0)*256 + t];
        float w1v = w2t[(size_t)(u4*4+1)*256 + t];
        float w2v = w2t[(size_t)(u4*4+2)*256 + t];
        float w3 = w2t[(size_t)(u4*4+3)*256 + t];
        #pragma unroll
        for (int rr = 0; rr < 8; ++rr) {
          float4 h4 = *(const float4*)&hsm[rr][u4*4];
          val[rr] += h4.x*w0 + h4.y*w1v + h4.z*w2v + h4.w*w3;
        }
      }
    }
    float gvv = lng[t], bv2 = lnb[t];
    for (int rr = 0; rr < 8; ++rr) {
      int r = r0 + rr;
      float2 sq = block_reduce2(val[rr], val[rr]*val[rr], red2);
      float mu  = sq.x * (1.f/256.f);
      float var = sq.y * (1.f/256.f) - mu*mu;
      float rs  = 1.f / sqrtf(var + 1e-5f);
      float ov  = (val[rr] - mu) * rs * gvv + bv2;
      qg[(size_t)r*256 + t] = ov;
      if (r < 2048) {
        ushort_t hi = f2bf(ov), lo = f2bf(ov - bf2f(hi));
        ushort_t* row = A2 + (size_t)r*768;
        row[t] = hi; row[256 + t] = lo; row[512 + t] = hi;
      }
    }
  }
  grid_bar(bar, phase);

  // ---- phase 2a: finalize (blocks 0..6): sg_hat + z_supp
  if (b < 7) {
    float* sg = (float*)smem;
    float2* red2 = (float2*)(smem + 1024);
    float acc = 0.f;
    #pragma unroll
    for (int s = 0; s < 5; ++s) acc += qg[(size_t)(2048+s)*256 + t];
    float sgv = acc * 0.2f;
    sg[t] = sgv;
    float2 nn = block_reduce2(sgv*sgv, 0.f, red2);
    if (b == 0) sg_hat[t] = sgv / fmaxf(sqrtf(nn.x), 1e-12f);
    __syncthreads();
    int u = b*256 + t;
    const float4* w4 = (const float4*)(whh_full + (size_t)u*512 + 256);
    float a = 0.f;
    #pragma unroll 4
    for (int j4 = 0; j4 < 64; ++j4) {
      float4 wv = w4[j4];
      float4 sv = *(const float4*)&sg[j4*4];
      a += dot4(wv, sv);
    }
    z_supp[u] = a;
    __syncthreads();
  }

  // ---- phase 2b: gemm0  Abuf = A2 @ B2ih^T + bias_s
  gemm_phase(A2, B2ih, Abuf, nullptr, bias_s, b % 28, b / 28, t, smem);
  grid_bar(bar, phase);

  // ---- phase 3: gate0 (z = A exactly; h_r = 0)
  gate_phase(Abuf, qg, cbuf, A2, 1, b, t);
  grid_bar(bar, phase);

  // ---- steps 1..3
  for (int s = 1; s <= 3; ++s) {
    if (s < 3) {
      gemm_phase(A2, B2hh, Zbuf, Abuf, z_supp, b % 28, b / 28, t, smem);
    } else if (b < 256) {
      // last step: only column slices {0:256, 512:768, 1024:1280, 1536:1792} are consumed
      int bxi = b & 15, by = b >> 4;
      int bx = (bxi >> 2) * 8 + (bxi & 3);
      gemm_phase(A2, B2hh, Zbuf, Abuf, z_supp, bx, by, t, smem);
    }
    grid_bar(bar, phase);
    if (s < 3) {
      gate_phase(Zbuf, qg, cbuf, A2, 0, b, t);
      grid_bar(bar, phase);
    } else {
      // fused final gate + cosine
      int wid = t >> 6, lane = t & 63;
      for (int r = b*4 + wid; r < 2048; r += NBLK*4) {
        const float* zr = Zbuf + (size_t)r * 1792;
        float d = 0.f, n2 = 0.f;
        #pragma unroll
        for (int i = 0; i < 4; ++i) {
          int j = lane + i*64;
          float zi = zr[j], zf = zr[512 + j], zg = zr[1024 + j], zo = zr[1536 + j];
          float cold = cbuf[(size_t)r*512 + j];
          float c2 = sigm(zf) * cold + sigm(zi) * tanhf(zg);
          float h = qg[(size_t)r*256 + j] + sigm(zo) * tanhf(c2);
          d += h * sg_hat[j];
          n2 += h * h;
        }
        #pragma unroll
        for (int off = 32; off; off >>= 1) { d += __shfl_down(d, off); n2 += __shfl_down(n2, off); }
        if (lane == 0) outv[r] = d / fmaxf(sqrtf(n2), 1e-12f);
      }
    }
  }
}

// ---------------------------------------------------------------- launch
extern "C" void kernel_launch(void* const* d_in, const int* in_sizes, int n_in,
                              void* d_out, int out_size, void* d_ws, size_t ws_size,
                              hipStream_t stream) {
  const float* emb   = (const float*)d_in[0];
  const float* gcnW  = (const float*)d_in[1];
  const float* gcnb  = (const float*)d_in[2];
  const float* gateW = (const float*)d_in[3];
  const float* gateb = (const float*)d_in[4];
  const float* sew1  = (const float*)d_in[5];
  const float* seb1  = (const float*)d_in[6];
  const float* sew2  = (const float*)d_in[7];
  const float* seb2  = (const float*)d_in[8];
  const float* lng   = (const float*)d_in[9];
  const float* lnb   = (const float*)d_in[10];
  const float* Wih   = (const float*)d_in[11];
  const float* Whh   = (const float*)d_in[12];
  const float* bih   = (const float*)d_in[13];
  const float* bhh   = (const float*)d_in[14];
  const int* query   = (const int*)d_in[15];
  const int* support = (const int*)d_in[16];
  const int* qlc     = (const int*)d_in[17];
  const int* qrc     = (const int*)d_in[19];
  const int* slc     = (const int*)d_in[21];
  const int* src     = (const int*)d_in[23];
  const int* knn     = (const int*)d_in[25];
  float* out = (float*)d_out;

  float* w = (float*)d_ws;
  size_t o = 0;
  auto alloc = [&](size_t n) { float* p = w + o; o += (n + 15) & ~(size_t)15; return p; };
  float* xbuf      = alloc((size_t)2056*256);
  float* query_g   = alloc((size_t)2056*256);
  float* sg_hat    = alloc(256);
  float* z_supp    = alloc(1792);
  float* cbuf      = alloc((size_t)2048*512);
  float* Abuf      = alloc((size_t)2048*1792);
  float* Zbuf      = alloc((size_t)2048*1792);
  float* w1t       = alloc(256*512);
  float* w2t       = alloc(512*256);
  float* bias_s    = alloc(1792);
  unsigned* bar    = (unsigned*)alloc(16);
  ushort_t* A2     = (ushort_t*)alloc((size_t)2048*768/2);
  ushort_t* B2ih   = (ushort_t*)alloc((size_t)1792*768/2);
  ushort_t* B2hh   = (ushort_t*)alloc((size_t)1792*768/2);
  (void)ws_size; (void)in_sizes; (void)n_in; (void)out_size;

  // 1) all weight prep + barrier zero in one launch
  prep_kernel<<<4616, 256, 0, stream>>>(sew1, sew2, Wih, Whh, bih, bhh,
                                        w1t, w2t, B2ih, B2hh, bias_s, bar);

  // 2) neighbor encoders (query rows 0..2047, support rows 2048..2052)
  enc_kernel<<<4106, 256, 0, stream>>>(emb, gcnW, gcnb, gateW, gateb, knn,
                                       query, support, qlc, qrc, slc, src, xbuf);

  // 3) fused persistent pipeline: qenc -> finalize -> 4x(gemm -> gate) -> cosine
  lstm_kernel<<<NBLK, 256, 0, stream>>>(xbuf, w1t, seb1, w2t, seb2, lng, lnb, Whh,
                                        B2ih, B2hh, bias_s,
                                        query_g, A2, z_supp, sg_hat,
                                        Abuf, Zbuf, cbuf, out, bar);
}

// Round 6
// 534.349 us; speedup vs baseline: 1.8693x; 1.8693x over previous
//
#include <hip/hip_runtime.h>

#define Vn 200000
#define PADI 199999

typedef unsigned short ushort_t;
typedef unsigned int uint_t;
typedef __attribute__((ext_vector_type(8))) short short8;
typedef _Float16 h8v __attribute__((ext_vector_type(8)));
typedef __attribute__((ext_vector_type(4))) float float4v;

__device__ __forceinline__ float sigm(float x) { return 1.f / (1.f + expf(-x)); }
__device__ __forceinline__ float dot4(float4 a, float4 b) {
  return a.x*b.x + a.y*b.y + a.z*b.z + a.w*b.w;
}
// fp16 bit pattern as ushort (buffers stay ushort; cast to h8v only at the MFMA)
__device__ __forceinline__ ushort_t f2h(float x) {
  return __builtin_bit_cast(ushort_t, (_Float16)x);
}

__device__ __forceinline__ float2 block_reduce2(float a, float b, float2* red) {
  #pragma unroll
  for (int off = 32; off; off >>= 1) { a += __shfl_down(a, off); b += __shfl_down(b, off); }
  __syncthreads();
  if ((threadIdx.x & 63) == 0) red[threadIdx.x >> 6] = make_float2(a, b);
  __syncthreads();
  float2 r;
  r.x = red[0].x + red[1].x + red[2].x + red[3].x;
  r.y = red[0].y + red[1].y + red[2].y + red[3].y;
  return r;
}

// ---------------------------------------------------------------- prep: all weight reshapes in one launch
__global__ __launch_bounds__(256) void prep_kernel(
    const float* __restrict__ sew1, const float* __restrict__ sew2,
    const float* __restrict__ Wih, const float* __restrict__ Whh,
    const float* __restrict__ bih, const float* __restrict__ bhh,
    float* __restrict__ w1t, float* __restrict__ w2t,
    ushort_t* __restrict__ Bih, ushort_t* __restrict__ Bhh,
    float* __restrict__ bias_s) {
  int b = blockIdx.x, t = threadIdx.x;
  if (b < 512) {                    // w1t[k*512+u] = sew1[u*256+k]
    int idx = b*256 + t;
    int c = idx >> 9, r = idx & 511;
    w1t[idx] = sew1[(size_t)r*256 + c];
  } else if (b < 1024) {            // w2t[u*256+t] = sew2[t*512+u]
    int idx = (b-512)*256 + t;
    int c = idx >> 8, r = idx & 255;
    w2t[idx] = sew2[(size_t)r*512 + c];
  } else if (b < 2816) {            // Bih[n][k] = fp16(Wih[n][k])
    int n = b - 1024;
    Bih[(size_t)n*256 + t] = f2h(Wih[(size_t)n*256 + t]);
  } else if (b < 4608) {            // Bhh[n][k] = fp16(Whh[n][k]), k<256
    int n = b - 2816;
    Bhh[(size_t)n*256 + t] = f2h(Whh[(size_t)n*512 + t]);
  } else {                          // bias_s = bih + bhh (first 1792)
    int i = (b-4608)*256 + t;
    if (i < 1792) bias_s[i] = bih[i] + bhh[i];
  }
}

// ---------------------------------------------------------------- neighbor encoder (round-3/4 proven version)
__global__ __launch_bounds__(256) void enc_kernel(
    const float* __restrict__ emb, const float* __restrict__ gcnW, const float* __restrict__ gcnb,
    const float* __restrict__ gateW, const float* __restrict__ gateb,
    const int* __restrict__ knn_tab,
    const int* __restrict__ query, const int* __restrict__ support,
    const int* __restrict__ qlc, const int* __restrict__ qrc,
    const int* __restrict__ slc, const int* __restrict__ src,
    float* __restrict__ xbuf) {   // 2056 x 256; support rows at 2048..2052
  __shared__ float center[128];
  __shared__ float simsu[192];    // 0..127 conn, 128..191 knn
  __shared__ int idr[128], ide[128];
  __shared__ int kidxs[64];
  __shared__ int sel[32], sel2[32];
  __shared__ int cnt1, cnt2;
  __shared__ float catbuf[256];
  __shared__ float knnA[128], knnB[128];
  __shared__ float part1[256], part2[256];
  __shared__ float structural[128], knnm[128];
  __shared__ float2 red2[4];

  int t = threadIdx.x;
  int g = blockIdx.x;
  int eid; const int* conn; float* outp;
  if (g < 2048)      { eid = query[2*g];                 conn = qlc + (size_t)g*256;      outp = xbuf + (size_t)g*256; }
  else if (g < 4096) { int b = g-2048; eid = query[2*b+1];  conn = qrc + (size_t)b*256;   outp = xbuf + (size_t)b*256 + 128; }
  else if (g < 4101) { int b = g-4096; eid = support[2*b];  conn = slc + (size_t)b*256;   outp = xbuf + (size_t)(2048+b)*256; }
  else               { int b = g-4101; eid = support[2*b+1]; conn = src + (size_t)b*256;  outp = xbuf + (size_t)(2048+b)*256 + 128; }
  if (eid < 0 || eid >= Vn) eid = PADI;

  if (t == 0) { cnt1 = 0; cnt2 = 0; }
  if (t < 128) {
    int2 cc = ((const int2*)conn)[t];
    idr[t] = cc.x; ide[t] = cc.y;
    center[t] = emb[(size_t)eid*128 + t];
  } else if (t < 192) {
    int kk = knn_tab[(size_t)eid*64 + (t-128)];
    kidxs[t-128] = (kk < 0 || kk >= Vn) ? PADI : kk;
  }
  __syncthreads();

  int gid = t >> 4, ll = t & 15;
  float4 cen0 = *(const float4*)&center[ll*8];
  float4 cen1 = *(const float4*)&center[ll*8 + 4];
  float cn2 = dot4(cen0, cen0) + dot4(cen1, cen1);
  #pragma unroll
  for (int off = 8; off; off >>= 1) cn2 += __shfl_down(cn2, off, 16);
  cn2 = __shfl(cn2, 0, 16);
  float cn = fmaxf(sqrtf(cn2), 1e-8f);

  // unified similarity loop: 3 rounds x 16 groups x 4 rows = 192
  #pragma unroll
  for (int it = 0; it < 3; ++it) {
    int rbase = it*64 + gid*4;
    int e[4];
    #pragma unroll
    for (int rr = 0; rr < 4; ++rr) {
      int n = rbase + rr;
      e[rr] = (n < 128) ? ide[n] : kidxs[n-128];
    }
    float d[4], m[4];
    #pragma unroll
    for (int rr = 0; rr < 4; ++rr) {
      const float4* p = (const float4*)(emb + (size_t)e[rr]*128);
      float4 a = p[ll*2], bb = p[ll*2+1];
      d[rr] = dot4(a, cen0) + dot4(bb, cen1);
      m[rr] = dot4(a, a) + dot4(bb, bb);
    }
    #pragma unroll
    for (int off = 8; off; off >>= 1) {
      #pragma unroll
      for (int rr = 0; rr < 4; ++rr) {
        d[rr] += __shfl_down(d[rr], off, 16);
        m[rr] += __shfl_down(m[rr], off, 16);
      }
    }
    if (ll == 0) {
      #pragma unroll
      for (int rr = 0; rr < 4; ++rr)
        simsu[rbase+rr] = d[rr] / (cn * fmaxf(sqrtf(m[rr]), 1e-8f));
    }
  }
  __syncthreads();

  // top-32 selections (rank count; jax.lax.top_k tie-break: lower index wins)
  if (t < 128) {
    float my = simsu[t];
    int c = 0;
    for (int j = 0; j < 128; ++j) {
      float sj = simsu[j];
      c += (sj > my) || (sj == my && j < t);
    }
    if (c < 32) { int p = atomicAdd(&cnt1, 1); sel[p] = t; }
  } else if (t < 192) {
    int i = t - 128;
    float my = simsu[128 + i];
    int c = 0;
    for (int j = 0; j < 64; ++j) {
      float sj = simsu[128 + j];
      c += (sj > my) || (sj == my && j < i);
    }
    if (c < 32) { int p = atomicAdd(&cnt2, 1); sel2[p] = i; }
  }
  __syncthreads();

  {
    int i = t & 127;
    float a0 = 0.f, a1 = 0.f, a2 = 0.f, a3 = 0.f;
    float k0 = 0.f, k1 = 0.f;
    if (t < 128) {
      #pragma unroll 2
      for (int k = 0; k < 32; k += 4) {
        a0 += emb[(size_t)idr[sel[k+0]]*128 + i];
        a1 += emb[(size_t)idr[sel[k+1]]*128 + i];
        a2 += emb[(size_t)idr[sel[k+2]]*128 + i];
        a3 += emb[(size_t)idr[sel[k+3]]*128 + i];
      }
      catbuf[i] = (a0+a1+a2+a3) * (1.f/32.f);
      #pragma unroll 2
      for (int k = 0; k < 16; k += 2) {
        k0 += emb[(size_t)kidxs[sel2[k+0]]*128 + i];
        k1 += emb[(size_t)kidxs[sel2[k+1]]*128 + i];
      }
      knnA[i] = k0 + k1;
    } else {
      #pragma unroll 2
      for (int k = 0; k < 32; k += 4) {
        a0 += emb[(size_t)ide[sel[k+0]]*128 + i];
        a1 += emb[(size_t)ide[sel[k+1]]*128 + i];
        a2 += emb[(size_t)ide[sel[k+2]]*128 + i];
        a3 += emb[(size_t)ide[sel[k+3]]*128 + i];
      }
      catbuf[128 + i] = (a0+a1+a2+a3) * (1.f/32.f);
      #pragma unroll 2
      for (int k = 16; k < 32; k += 2) {
        k0 += emb[(size_t)kidxs[sel2[k+0]]*128 + i];
        k1 += emb[(size_t)kidxs[sel2[k+1]]*128 + i];
      }
      knnB[i] = k0 + k1;
    }
  }
  __syncthreads();

  {
    int i = t & 127, half = t >> 7;
    const float4* w1p = (const float4*)(gcnW + (size_t)i*256 + half*128);
    const float4* c1p = (const float4*)(catbuf + half*128);
    float p1 = 0.f;
    #pragma unroll 8
    for (int j = 0; j < 32; ++j) {
      float4 w = w1p[j], a = c1p[j];
      p1 += dot4(w, a);
    }
    const float4* w2p = (const float4*)(gcnW + (size_t)i*256 + 128 + half*64);
    const float4* kap = (const float4*)(knnA + half*64);
    const float4* kbp = (const float4*)(knnB + half*64);
    float p2 = 0.f;
    #pragma unroll 8
    for (int j = 0; j < 16; ++j) {
      float4 w = w2p[j], xa = kap[j], xb = kbp[j];
      float4 s = make_float4(xa.x+xb.x, xa.y+xb.y, xa.z+xb.z, xa.w+xb.w);
      p2 += dot4(w, s);
    }
    part1[t] = p1;
    part2[t] = p2 * (1.f/32.f);
  }
  __syncthreads();
  if (t < 128) {
    structural[t] = tanhf(part1[t] + part1[t+128] + gcnb[t]);
    knnm[t]       = tanhf(part2[t] + part2[t+128] + gcnb[t]);
  }
  __syncthreads();

  float gv = (t < 128) ? structural[t]*gateW[t] : knnm[t-128]*gateW[t];
  float2 rr = block_reduce2(gv, 0.f, red2);
  float alpha = sigm(rr.x + gateb[0]);
  if (t < 128) outp[t] = (1.f - alpha)*structural[t] + alpha*knnm[t];
}

// ---------------------------------------------------------------- MLP+LN on 2056 rows, emits fp16-bit rows
__global__ __launch_bounds__(256) void qenc_kernel(
    const float* __restrict__ xin, const float* __restrict__ w1t, const float* __restrict__ b1,
    const float* __restrict__ w2t, const float* __restrict__ b2,
    const float* __restrict__ lng, const float* __restrict__ lnb,
    float* __restrict__ xout, ushort_t* __restrict__ Ah) {
  __shared__ float xs[8][256];
  __shared__ float hsm[8][512];
  __shared__ float2 red2[4];
  int t = threadIdx.x;
  int r0 = blockIdx.x * 8;
  #pragma unroll
  for (int rr = 0; rr < 8; ++rr) xs[rr][t] = xin[(size_t)(r0+rr)*256 + t];
  __syncthreads();
  #pragma unroll
  for (int uo = 0; uo < 512; uo += 256) {
    int u = uo + t;
    float bv = b1[u];
    float acc[8];
    #pragma unroll
    for (int rr = 0; rr < 8; ++rr) acc[rr] = bv;
    for (int j4 = 0; j4 < 64; ++j4) {
      float w0 = w1t[(size_t)(j4*4+0)*512 + u];
      float w1v = w1t[(size_t)(j4*4+1)*512 + u];
      float w2v = w1t[(size_t)(j4*4+2)*512 + u];
      float w3 = w1t[(size_t)(j4*4+3)*512 + u];
      #pragma unroll
      for (int rr = 0; rr < 8; ++rr) {
        float4 x = *(const float4*)&xs[rr][j4*4];
        acc[rr] += x.x*w0 + x.y*w1v + x.z*w2v + x.w*w3;
      }
    }
    #pragma unroll
    for (int rr = 0; rr < 8; ++rr) hsm[rr][u] = fmaxf(acc[rr], 0.f);
  }
  __syncthreads();
  float val[8];
  {
    float bv = b2[t];
    #pragma unroll
    for (int rr = 0; rr < 8; ++rr) val[rr] = bv + xs[rr][t];
    for (int u4 = 0; u4 < 128; ++u4) {
      float w0 = w2t[(size_t)(u4*4+0)*256 + t];
      float w1v = w2t[(size_t)(u4*4+1)*256 + t];
      float w2v = w2t[(size_t)(u4*4+2)*256 + t];
      float w3 = w2t[(size_t)(u4*4+3)*256 + t];
      #pragma unroll
      for (int rr = 0; rr < 8; ++rr) {
        float4 h4 = *(const float4*)&hsm[rr][u4*4];
        val[rr] += h4.x*w0 + h4.y*w1v + h4.z*w2v + h4.w*w3;
      }
    }
  }
  float gvv = lng[t], bv2 = lnb[t];
  for (int rr = 0; rr < 8; ++rr) {
    int r = r0 + rr;
    float2 sq = block_reduce2(val[rr], val[rr]*val[rr], red2);
    float mu  = sq.x * (1.f/256.f);
    float var = sq.y * (1.f/256.f) - mu*mu;
    float rs  = 1.f / sqrtf(var + 1e-5f);
    float ov  = (val[rr] - mu) * rs * gvv + bv2;
    xout[(size_t)r*256 + t] = ov;
    if (r < 2048) Ah[(size_t)r*256 + t] = f2h(ov);
  }
}

// ---------------------------------------------------------------- finalize: sg_hat + z_supp
__global__ __launch_bounds__(256) void finalize_kernel(
    const float* __restrict__ qout, const float* __restrict__ whh,
    float* __restrict__ sg_hat, float* __restrict__ z_supp) {
  __shared__ float sg[256];
  __shared__ float2 red2[4];
  int t = threadIdx.x;
  float acc = 0.f;
  #pragma unroll
  for (int s = 0; s < 5; ++s) acc += qout[(size_t)(2048+s)*256 + t];
  float sgv = acc * 0.2f;
  sg[t] = sgv;
  float2 nn = block_reduce2(sgv*sgv, 0.f, red2);
  if (blockIdx.x == 0) sg_hat[t] = sgv / fmaxf(sqrtf(nn.x), 1e-12f);
  __syncthreads();
  int u = blockIdx.x*256 + t;
  const float4* w4 = (const float4*)(whh + (size_t)u*512 + 256);
  float a = 0.f;
  #pragma unroll 4
  for (int j4 = 0; j4 < 64; ++j4) {
    float4 wv = w4[j4];
    float4 sv = *(const float4*)&sg[j4*4];
    a += dot4(wv, sv);
  }
  z_supp[u] = a;
}

// ---------------------------------------------------------------- fp16 MFMA GEMM (ushort machinery from the
// proven round-3 bf16 kernel; only K=256 and the intrinsic changed)
// C[m,n] = A[M,256] @ BT[N,256]^T (+addmat)(+cv); remap compresses bx over tiles {0,1,4,5,8,9,12,13}
__global__ __launch_bounds__(256) void gemm_f16_kernel(
    const ushort_t* __restrict__ A, const ushort_t* __restrict__ BT,
    float* __restrict__ C, const float* __restrict__ addmat,
    const float* __restrict__ cv, int remap) {
  __shared__ ushort_t As[128*40];
  __shared__ ushort_t Bs[128*40];
  int t = threadIdx.x;
  int bx = blockIdx.x;
  if (remap) bx = (bx >> 1)*4 + (bx & 1);
  int m0 = blockIdx.y * 128, n0 = bx * 128;
  int wid = t >> 6, lane = t & 63;
  int wm = (wid >> 1) * 64, wn = (wid & 1) * 64;
  int q = lane >> 4, fr = lane & 15;
  float4v acc[4][4];
  #pragma unroll
  for (int i = 0; i < 4; ++i)
    #pragma unroll
    for (int j = 0; j < 4; ++j) acc[i][j] = (float4v)0.f;

  for (int k0 = 0; k0 < 256; k0 += 32) {
    #pragma unroll
    for (int rnd = 0; rnd < 2; ++rnd) {
      int idx = rnd*256 + t;
      int row = idx >> 2, ch = idx & 3;
      *(short8*)&As[row*40 + ch*8] = *(const short8*)(A + (size_t)(m0+row)*256 + k0 + ch*8);
      *(short8*)&Bs[row*40 + ch*8] = *(const short8*)(BT + (size_t)(n0+row)*256 + k0 + ch*8);
    }
    __syncthreads();
    short8 af[4], bg[4];
    #pragma unroll
    for (int tm = 0; tm < 4; ++tm) af[tm] = *(const short8*)&As[(wm + tm*16 + fr)*40 + q*8];
    #pragma unroll
    for (int tn = 0; tn < 4; ++tn) bg[tn] = *(const short8*)&Bs[(wn + tn*16 + fr)*40 + q*8];
    #pragma unroll
    for (int tm = 0; tm < 4; ++tm)
      #pragma unroll
      for (int tn = 0; tn < 4; ++tn)
        acc[tm][tn] = __builtin_amdgcn_mfma_f32_16x16x32_f16(
            __builtin_bit_cast(h8v, af[tm]), __builtin_bit_cast(h8v, bg[tn]),
            acc[tm][tn], 0, 0, 0);
    __syncthreads();
  }

  // epilogue: C/D layout col = lane&15, row = q*4 + reg
  #pragma unroll
  for (int tm = 0; tm < 4; ++tm) {
    int gm = m0 + wm + tm*16 + q*4;
    #pragma unroll
    for (int tn = 0; tn < 4; ++tn) {
      int gn = n0 + wn + tn*16 + fr;
      float cvv = cv ? cv[gn] : 0.f;
      #pragma unroll
      for (int reg = 0; reg < 4; ++reg) {
        size_t off = (size_t)(gm + reg) * 1792 + gn;
        float x = acc[tm][tn][reg] + cvv;
        if (addmat) x += addmat[off];
        C[off] = x;
      }
    }
  }
}

// ---------------------------------------------------------------- LSTM gates (Z stride 1792), writes fp16-bit rows
__global__ __launch_bounds__(256) void gate_kernel(
    const float* __restrict__ Z, const float* __restrict__ qg,
    float* __restrict__ c, ushort_t* __restrict__ Ah, int step0) {
  int idx = blockIdx.x * 256 + threadIdx.x;   // 2048*512
  int r = idx >> 9, j = idx & 511;
  const float* zr = Z + (size_t)r * 1792;
  float zi = zr[j], zf = zr[512 + j], zg = zr[1024 + j];
  float cold = step0 ? 0.f : c[idx];
  float c2 = sigm(zf) * cold + sigm(zi) * tanhf(zg);
  c[idx] = c2;
  if (j < 256) {
    float zo = zr[1536 + j];
    float h = qg[(size_t)r*256 + j] + sigm(zo) * tanhf(c2);
    Ah[(size_t)r*256 + j] = f2h(h);
  }
}

// ---------------------------------------------------------------- final gate + cosine fused
__global__ __launch_bounds__(256) void gatecos_kernel(
    const float* __restrict__ Z, const float* __restrict__ qg, const float* __restrict__ c,
    const float* __restrict__ sgh, float* __restrict__ out) {
  int wid = threadIdx.x >> 6, lane = threadIdx.x & 63;
  int r = blockIdx.x*4 + wid;
  const float* zr = Z + (size_t)r * 1792;
  float d = 0.f, n2 = 0.f;
  #pragma unroll
  for (int i = 0; i < 4; ++i) {
    int j = lane + i*64;
    float zi = zr[j], zf = zr[512 + j], zg = zr[1024 + j], zo = zr[1536 + j];
    float cold = c[(size_t)r*512 + j];
    float c2 = sigm(zf) * cold + sigm(zi) * tanhf(zg);
    float h = qg[(size_t)r*256 + j] + sigm(zo) * tanhf(c2);
    d += h * sgh[j];
    n2 += h * h;
  }
  #pragma unroll
  for (int off = 32; off; off >>= 1) { d += __shfl_down(d, off); n2 += __shfl_down(n2, off); }
  if (lane == 0) out[r] = d / fmaxf(sqrtf(n2), 1e-12f);
}

// ---------------------------------------------------------------- launch
extern "C" void kernel_launch(void* const* d_in, const int* in_sizes, int n_in,
                              void* d_out, int out_size, void* d_ws, size_t ws_size,
                              hipStream_t stream) {
  const float* emb   = (const float*)d_in[0];
  const float* gcnW  = (const float*)d_in[1];
  const float* gcnb  = (const float*)d_in[2];
  const float* gateW = (const float*)d_in[3];
  const float* gateb = (const float*)d_in[4];
  const float* sew1  = (const float*)d_in[5];
  const float* seb1  = (const float*)d_in[6];
  const float* sew2  = (const float*)d_in[7];
  const float* seb2  = (const float*)d_in[8];
  const float* lng   = (const float*)d_in[9];
  const float* lnb   = (const float*)d_in[10];
  const float* Wih   = (const float*)d_in[11];
  const float* Whh   = (const float*)d_in[12];
  const float* bih   = (const float*)d_in[13];
  const float* bhh   = (const float*)d_in[14];
  const int* query   = (const int*)d_in[15];
  const int* support = (const int*)d_in[16];
  const int* qlc     = (const int*)d_in[17];
  const int* qrc     = (const int*)d_in[19];
  const int* slc     = (const int*)d_in[21];
  const int* src     = (const int*)d_in[23];
  const int* knn     = (const int*)d_in[25];
  float* out = (float*)d_out;

  float* w = (float*)d_ws;
  size_t o = 0;
  auto alloc = [&](size_t n) { float* p = w + o; o += (n + 15) & ~(size_t)15; return p; };
  float* xbuf      = alloc((size_t)2056*256);
  float* query_g   = alloc((size_t)2056*256);
  float* sg_hat    = alloc(256);
  float* z_supp    = alloc(2048);
  float* cbuf      = alloc((size_t)2048*512);
  float* Abuf      = alloc((size_t)2048*1792);
  float* Zbuf      = alloc((size_t)2048*1792);
  float* w1t       = alloc(256*512);
  float* w2t       = alloc(512*256);
  float* bias_s    = alloc(2048);
  ushort_t* Ah     = (ushort_t*)alloc((size_t)2048*128);   // 2048x256 fp16 bits
  ushort_t* Bih    = (ushort_t*)alloc((size_t)1792*128);   // 1792x256 fp16 bits
  ushort_t* Bhh    = (ushort_t*)alloc((size_t)1792*128);
  (void)ws_size; (void)in_sizes; (void)n_in; (void)out_size;

  // 1) all weight prep in one launch
  prep_kernel<<<4615, 256, 0, stream>>>(sew1, sew2, Wih, Whh, bih, bhh,
                                        w1t, w2t, Bih, Bhh, bias_s);

  // 2) neighbor encoders (query rows 0..2047, support rows 2048..2052)
  enc_kernel<<<4106, 256, 0, stream>>>(emb, gcnW, gcnb, gateW, gateb, knn,
                                       query, support, qlc, qrc, slc, src, xbuf);

  // 3) MLP+LN on 2056 rows, emits fp16 A for rows<2048
  qenc_kernel<<<257, 256, 0, stream>>>(xbuf, w1t, seb1, w2t, seb2, lng, lnb, query_g, Ah);

  // 4) support aggregation: sg_hat + z_supp
  finalize_kernel<<<7, 256, 0, stream>>>(query_g, Whh, sg_hat, z_supp);

  // 5) LSTM matching with fp16 MFMA GEMMs (K=256, N=1792)
  gemm_f16_kernel<<<dim3(14,16), 256, 0, stream>>>(Ah, Bih, Abuf, nullptr, bias_s, 0);
  gate_kernel<<<4096, 256, 0, stream>>>(Abuf, query_g, cbuf, Ah, 1);
  for (int s = 1; s < 4; ++s) {
    if (s < 3) {
      gemm_f16_kernel<<<dim3(14,16), 256, 0, stream>>>(Ah, Bhh, Zbuf, Abuf, z_supp, 0);
      gate_kernel<<<4096, 256, 0, stream>>>(Zbuf, query_g, cbuf, Ah, 0);
    } else {
      // last step: only column tiles {0,1,4,5,8,9,12,13} are consumed by gatecos
      gemm_f16_kernel<<<dim3(8,16), 256, 0, stream>>>(Ah, Bhh, Zbuf, Abuf, z_supp, 1);
      gatecos_kernel<<<512, 256, 0, stream>>>(Zbuf, query_g, cbuf, sg_hat, out);
    }
  }
}

// Round 7
// 511.127 us; speedup vs baseline: 1.9543x; 1.0454x over previous
//
#include <hip/hip_runtime.h>

#define Vn 200000
#define PADI 199999

typedef unsigned short ushort_t;
typedef unsigned int uint_t;
typedef __attribute__((ext_vector_type(8))) short short8;
typedef _Float16 h8v __attribute__((ext_vector_type(8)));
typedef __attribute__((ext_vector_type(4))) float float4v;

__device__ __forceinline__ float sigm(float x) { return 1.f / (1.f + expf(-x)); }
__device__ __forceinline__ float dot4(float4 a, float4 b) {
  return a.x*b.x + a.y*b.y + a.z*b.z + a.w*b.w;
}
__device__ __forceinline__ ushort_t f2h(float x) {
  return __builtin_bit_cast(ushort_t, (_Float16)x);
}
// permuted B-row order: n = g*128 + s*32 + q  ->  orig = s*512 + g*32 + q
// (s: 0=i,1=f,2=g,3=o ; g = h-column group of 32)
__device__ __forceinline__ int permrow(int n) {
  int g = n >> 7, s = (n >> 5) & 3, q = n & 31;
  return s*512 + g*32 + q;
}

__device__ __forceinline__ float2 block_reduce2(float a, float b, float2* red) {
  #pragma unroll
  for (int off = 32; off; off >>= 1) { a += __shfl_down(a, off); b += __shfl_down(b, off); }
  __syncthreads();
  if ((threadIdx.x & 63) == 0) red[threadIdx.x >> 6] = make_float2(a, b);
  __syncthreads();
  float2 r;
  r.x = red[0].x + red[1].x + red[2].x + red[3].x;
  r.y = red[0].y + red[1].y + red[2].y + red[3].y;
  return r;
}

// ---------------------------------------------------------------- enc + prep fused (disjoint block ranges)
__global__ __launch_bounds__(256) void encprep_kernel(
    const float* __restrict__ emb, const float* __restrict__ gcnW, const float* __restrict__ gcnb,
    const float* __restrict__ gateW, const float* __restrict__ gateb,
    const int* __restrict__ knn_tab,
    const int* __restrict__ query, const int* __restrict__ support,
    const int* __restrict__ qlc, const int* __restrict__ qrc,
    const int* __restrict__ slc, const int* __restrict__ src,
    float* __restrict__ xbuf,
    const float* __restrict__ sew1, const float* __restrict__ sew2,
    const float* __restrict__ Wih, const float* __restrict__ Whh,
    const float* __restrict__ bih, const float* __restrict__ bhh,
    float* __restrict__ w1t, float* __restrict__ w2t,
    ushort_t* __restrict__ Bih, ushort_t* __restrict__ Bhh,
    float* __restrict__ bias_p) {
  __shared__ float center[128];
  __shared__ float simsu[192];
  __shared__ int idr[128], ide[128];
  __shared__ int kidxs[64];
  __shared__ int sel[32], sel2[32];
  __shared__ int cnt1, cnt2;
  __shared__ float catbuf[256];
  __shared__ float knnA[128], knnB[128];
  __shared__ float part1[256], part2[256];
  __shared__ float structural[128], knnm[128];
  __shared__ float2 red2[4];

  int t = threadIdx.x;
  int g = blockIdx.x;

  if (g >= 4106) {                  // ---- prep blocks
    int b2 = g - 4106;
    if (b2 < 512) {                 // w1t[k*512+u] = sew1[u*256+k]
      int idx = b2*256 + t;
      int c = idx >> 9, r = idx & 511;
      w1t[idx] = sew1[(size_t)r*256 + c];
    } else if (b2 < 1024) {         // w2t[u*256+tt] = sew2[tt*512+u]
      int idx = (b2-512)*256 + t;
      int c = idx >> 8, r = idx & 255;
      w2t[idx] = sew2[(size_t)r*512 + c];
    } else if (b2 < 3072) {         // Bih permuted
      int n = b2 - 1024;
      Bih[(size_t)n*256 + t] = f2h(Wih[(size_t)permrow(n)*256 + t]);
    } else if (b2 < 5120) {         // Bhh permuted (k<256 slice)
      int n = b2 - 3072;
      Bhh[(size_t)n*256 + t] = f2h(Whh[(size_t)permrow(n)*512 + t]);
    } else {                        // bias permuted
      int i = (b2-5120)*256 + t;
      int o2 = permrow(i);
      bias_p[i] = bih[o2] + bhh[o2];
    }
    return;
  }

  int eid; const int* conn; float* outp;
  if (g < 2048)      { eid = query[2*g];                 conn = qlc + (size_t)g*256;      outp = xbuf + (size_t)g*256; }
  else if (g < 4096) { int b = g-2048; eid = query[2*b+1];  conn = qrc + (size_t)b*256;   outp = xbuf + (size_t)b*256 + 128; }
  else if (g < 4101) { int b = g-4096; eid = support[2*b];  conn = slc + (size_t)b*256;   outp = xbuf + (size_t)(2048+b)*256; }
  else               { int b = g-4101; eid = support[2*b+1]; conn = src + (size_t)b*256;  outp = xbuf + (size_t)(2048+b)*256 + 128; }
  if (eid < 0 || eid >= Vn) eid = PADI;

  if (t == 0) { cnt1 = 0; cnt2 = 0; }
  if (t < 128) {
    int2 cc = ((const int2*)conn)[t];
    idr[t] = cc.x; ide[t] = cc.y;
    center[t] = emb[(size_t)eid*128 + t];
  } else if (t < 192) {
    int kk = knn_tab[(size_t)eid*64 + (t-128)];
    kidxs[t-128] = (kk < 0 || kk >= Vn) ? PADI : kk;
  }
  __syncthreads();

  int gid = t >> 4, ll = t & 15;
  float4 cen0 = *(const float4*)&center[ll*8];
  float4 cen1 = *(const float4*)&center[ll*8 + 4];
  float cn2 = dot4(cen0, cen0) + dot4(cen1, cen1);
  #pragma unroll
  for (int off = 8; off; off >>= 1) cn2 += __shfl_down(cn2, off, 16);
  cn2 = __shfl(cn2, 0, 16);
  float cn = fmaxf(sqrtf(cn2), 1e-8f);

  #pragma unroll
  for (int it = 0; it < 3; ++it) {
    int rbase = it*64 + gid*4;
    int e[4];
    #pragma unroll
    for (int rr = 0; rr < 4; ++rr) {
      int n = rbase + rr;
      e[rr] = (n < 128) ? ide[n] : kidxs[n-128];
    }
    float d[4], m[4];
    #pragma unroll
    for (int rr = 0; rr < 4; ++rr) {
      const float4* p = (const float4*)(emb + (size_t)e[rr]*128);
      float4 a = p[ll*2], bb = p[ll*2+1];
      d[rr] = dot4(a, cen0) + dot4(bb, cen1);
      m[rr] = dot4(a, a) + dot4(bb, bb);
    }
    #pragma unroll
    for (int off = 8; off; off >>= 1) {
      #pragma unroll
      for (int rr = 0; rr < 4; ++rr) {
        d[rr] += __shfl_down(d[rr], off, 16);
        m[rr] += __shfl_down(m[rr], off, 16);
      }
    }
    if (ll == 0) {
      #pragma unroll
      for (int rr = 0; rr < 4; ++rr)
        simsu[rbase+rr] = d[rr] / (cn * fmaxf(sqrtf(m[rr]), 1e-8f));
    }
  }
  __syncthreads();

  if (t < 128) {
    float my = simsu[t];
    int c = 0;
    for (int j = 0; j < 128; ++j) {
      float sj = simsu[j];
      c += (sj > my) || (sj == my && j < t);
    }
    if (c < 32) { int p = atomicAdd(&cnt1, 1); sel[p] = t; }
  } else if (t < 192) {
    int i = t - 128;
    float my = simsu[128 + i];
    int c = 0;
    for (int j = 0; j < 64; ++j) {
      float sj = simsu[128 + j];
      c += (sj > my) || (sj == my && j < i);
    }
    if (c < 32) { int p = atomicAdd(&cnt2, 1); sel2[p] = i; }
  }
  __syncthreads();

  {
    int i = t & 127;
    float a0 = 0.f, a1 = 0.f, a2 = 0.f, a3 = 0.f;
    float k0 = 0.f, k1 = 0.f;
    if (t < 128) {
      #pragma unroll 2
      for (int k = 0; k < 32; k += 4) {
        a0 += emb[(size_t)idr[sel[k+0]]*128 + i];
        a1 += emb[(size_t)idr[sel[k+1]]*128 + i];
        a2 += emb[(size_t)idr[sel[k+2]]*128 + i];
        a3 += emb[(size_t)idr[sel[k+3]]*128 + i];
      }
      catbuf[i] = (a0+a1+a2+a3) * (1.f/32.f);
      #pragma unroll 2
      for (int k = 0; k < 16; k += 2) {
        k0 += emb[(size_t)kidxs[sel2[k+0]]*128 + i];
        k1 += emb[(size_t)kidxs[sel2[k+1]]*128 + i];
      }
      knnA[i] = k0 + k1;
    } else {
      #pragma unroll 2
      for (int k = 0; k < 32; k += 4) {
        a0 += emb[(size_t)ide[sel[k+0]]*128 + i];
        a1 += emb[(size_t)ide[sel[k+1]]*128 + i];
        a2 += emb[(size_t)ide[sel[k+2]]*128 + i];
        a3 += emb[(size_t)ide[sel[k+3]]*128 + i];
      }
      catbuf[128 + i] = (a0+a1+a2+a3) * (1.f/32.f);
      #pragma unroll 2
      for (int k = 16; k < 32; k += 2) {
        k0 += emb[(size_t)kidxs[sel2[k+0]]*128 + i];
        k1 += emb[(size_t)kidxs[sel2[k+1]]*128 + i];
      }
      knnB[i] = k0 + k1;
    }
  }
  __syncthreads();

  {
    int i = t & 127, half = t >> 7;
    const float4* w1p = (const float4*)(gcnW + (size_t)i*256 + half*128);
    const float4* c1p = (const float4*)(catbuf + half*128);
    float p1 = 0.f;
    #pragma unroll 8
    for (int j = 0; j < 32; ++j) {
      float4 w = w1p[j], a = c1p[j];
      p1 += dot4(w, a);
    }
    const float4* w2p = (const float4*)(gcnW + (size_t)i*256 + 128 + half*64);
    const float4* kap = (const float4*)(knnA + half*64);
    const float4* kbp = (const float4*)(knnB + half*64);
    float p2 = 0.f;
    #pragma unroll 8
    for (int j = 0; j < 16; ++j) {
      float4 w = w2p[j], xa = kap[j], xb = kbp[j];
      float4 s = make_float4(xa.x+xb.x, xa.y+xb.y, xa.z+xb.z, xa.w+xb.w);
      p2 += dot4(w, s);
    }
    part1[t] = p1;
    part2[t] = p2 * (1.f/32.f);
  }
  __syncthreads();
  if (t < 128) {
    structural[t] = tanhf(part1[t] + part1[t+128] + gcnb[t]);
    knnm[t]       = tanhf(part2[t] + part2[t+128] + gcnb[t]);
  }
  __syncthreads();

  float gv = (t < 128) ? structural[t]*gateW[t] : knnm[t-128]*gateW[t];
  float2 rr = block_reduce2(gv, 0.f, red2);
  float alpha = sigm(rr.x + gateb[0]);
  if (t < 128) outp[t] = (1.f - alpha)*structural[t] + alpha*knnm[t];
}

// ---------------------------------------------------------------- MLP+LN on 2056 rows, emits fp16-bit rows
__global__ __launch_bounds__(256) void qenc_kernel(
    const float* __restrict__ xin, const float* __restrict__ w1t, const float* __restrict__ b1,
    const float* __restrict__ w2t, const float* __restrict__ b2,
    const float* __restrict__ lng, const float* __restrict__ lnb,
    float* __restrict__ xout, ushort_t* __restrict__ Ah) {
  __shared__ float xs[8][256];
  __shared__ float hsm[8][512];
  __shared__ float2 red2[4];
  int t = threadIdx.x;
  int r0 = blockIdx.x * 8;
  #pragma unroll
  for (int rr = 0; rr < 8; ++rr) xs[rr][t] = xin[(size_t)(r0+rr)*256 + t];
  __syncthreads();
  #pragma unroll
  for (int uo = 0; uo < 512; uo += 256) {
    int u = uo + t;
    float bv = b1[u];
    float acc[8];
    #pragma unroll
    for (int rr = 0; rr < 8; ++rr) acc[rr] = bv;
    for (int j4 = 0; j4 < 64; ++j4) {
      float w0 = w1t[(size_t)(j4*4+0)*512 + u];
      float w1v = w1t[(size_t)(j4*4+1)*512 + u];
      float w2v = w1t[(size_t)(j4*4+2)*512 + u];
      float w3 = w1t[(size_t)(j4*4+3)*512 + u];
      #pragma unroll
      for (int rr = 0; rr < 8; ++rr) {
        float4 x = *(const float4*)&xs[rr][j4*4];
        acc[rr] += x.x*w0 + x.y*w1v + x.z*w2v + x.w*w3;
      }
    }
    #pragma unroll
    for (int rr = 0; rr < 8; ++rr) hsm[rr][u] = fmaxf(acc[rr], 0.f);
  }
  __syncthreads();
  float val[8];
  {
    float bv = b2[t];
    #pragma unroll
    for (int rr = 0; rr < 8; ++rr) val[rr] = bv + xs[rr][t];
    for (int u4 = 0; u4 < 128; ++u4) {
      float w0 = w2t[(size_t)(u4*4+0)*256 + t];
      float w1v = w2t[(size_t)(u4*4+1)*256 + t];
      float w2v = w2t[(size_t)(u4*4+2)*256 + t];
      float w3 = w2t[(size_t)(u4*4+3)*256 + t];
      #pragma unroll
      for (int rr = 0; rr < 8; ++rr) {
        float4 h4 = *(const float4*)&hsm[rr][u4*4];
        val[rr] += h4.x*w0 + h4.y*w1v + h4.z*w2v + h4.w*w3;
      }
    }
  }
  float gvv = lng[t], bv2 = lnb[t];
  for (int rr = 0; rr < 8; ++rr) {
    int r = r0 + rr;
    float2 sq = block_reduce2(val[rr], val[rr]*val[rr], red2);
    float mu  = sq.x * (1.f/256.f);
    float var = sq.y * (1.f/256.f) - mu*mu;
    float rs  = 1.f / sqrtf(var + 1e-5f);
    float ov  = (val[rr] - mu) * rs * gvv + bv2;
    xout[(size_t)r*256 + t] = ov;
    if (r < 2048) Ah[(size_t)r*256 + t] = f2h(ov);
  }
}

// ---------------------------------------------------------------- GEMM + fused gate epilogue
// A[2048,256] fp16-bits @ BT[2048,256]^T, permuted columns: tile bx holds [i|f|g|o] for
// h-cols bx*32..bx*32+31. mode 0: +bias, c_old=0, write Abuf+c+AhOut, bx==16 stripe = finalize.
// mode 1: +z_supp +Abuf, rw c, write AhOut. mode 2 (final, bx<8): +z_supp +Abuf, read c, write hOut.
__global__ __launch_bounds__(256) void gemmgate_kernel(
    const ushort_t* __restrict__ A, const ushort_t* __restrict__ BT,
    float* __restrict__ Abuf, const float* __restrict__ cv,
    const float* __restrict__ qg, float* __restrict__ cstate,
    ushort_t* __restrict__ AhOut, float* __restrict__ hOut,
    const float* __restrict__ whh_full, float* __restrict__ sg_hat,
    float* __restrict__ z_supp, int mode) {
  __shared__ __align__(16) char arena[64*132*4];   // staging (20.5KB) then epilogue transpose (33.8KB)
  __shared__ float sg[256];
  __shared__ float2 red2[4];
  int t = threadIdx.x;
  int bx = blockIdx.x, by = blockIdx.y;

  if (bx == 16) {                   // ---- finalize stripe (mode-0 launch only)
    if (by > 8) return;
    float acc = 0.f;
    #pragma unroll
    for (int s = 0; s < 5; ++s) acc += qg[(size_t)(2048+s)*256 + t];
    sg[t] = acc * 0.2f;
    __syncthreads();
    if (by < 8) {                   // z_supp (permuted)
      int up = by*256 + t;
      const float4* w4 = (const float4*)(whh_full + (size_t)permrow(up)*512 + 256);
      float a = 0.f;
      #pragma unroll 4
      for (int j4 = 0; j4 < 64; ++j4) {
        float4 wv = w4[j4];
        float4 sv = *(const float4*)&sg[j4*4];
        a += dot4(wv, sv);
      }
      z_supp[up] = a;
    } else {                        // sg_hat
      float sgv = sg[t];
      float2 nn = block_reduce2(sgv*sgv, 0.f, red2);
      sg_hat[t] = sgv / fmaxf(sqrtf(nn.x), 1e-12f);
    }
    return;
  }

  ushort_t* As = (ushort_t*)arena;
  ushort_t* Bs = As + 128*40;
  int m0 = by * 128, n0 = bx * 128;
  int wid = t >> 6, lane = t & 63;
  int wm = (wid >> 1) * 64, wn = (wid & 1) * 64;
  int q = lane >> 4, fr = lane & 15;
  float4v acc[4][4];
  #pragma unroll
  for (int i = 0; i < 4; ++i)
    #pragma unroll
    for (int j = 0; j < 4; ++j) acc[i][j] = (float4v)0.f;

  for (int k0 = 0; k0 < 256; k0 += 32) {
    #pragma unroll
    for (int rnd = 0; rnd < 2; ++rnd) {
      int idx = rnd*256 + t;
      int row = idx >> 2, ch = idx & 3;
      *(short8*)&As[row*40 + ch*8] = *(const short8*)(A + (size_t)(m0+row)*256 + k0 + ch*8);
      *(short8*)&Bs[row*40 + ch*8] = *(const short8*)(BT + (size_t)(n0+row)*256 + k0 + ch*8);
    }
    __syncthreads();
    short8 af[4], bg[4];
    #pragma unroll
    for (int tm = 0; tm < 4; ++tm) af[tm] = *(const short8*)&As[(wm + tm*16 + fr)*40 + q*8];
    #pragma unroll
    for (int tn = 0; tn < 4; ++tn) bg[tn] = *(const short8*)&Bs[(wn + tn*16 + fr)*40 + q*8];
    #pragma unroll
    for (int tm = 0; tm < 4; ++tm)
      #pragma unroll
      for (int tn = 0; tn < 4; ++tn)
        acc[tm][tn] = __builtin_amdgcn_mfma_f32_16x16x32_f16(
            __builtin_bit_cast(h8v, af[tm]), __builtin_bit_cast(h8v, bg[tn]),
            acc[tm][tn], 0, 0, 0);
    __syncthreads();
  }

  // x = acc + cv[gn] (+ Abuf addmat for mode>=1); mode 0 also stores Abuf = x
  #pragma unroll
  for (int tm = 0; tm < 4; ++tm) {
    int gm = m0 + wm + tm*16 + q*4;
    #pragma unroll
    for (int tn = 0; tn < 4; ++tn) {
      int gn = n0 + wn + tn*16 + fr;
      float cvv = cv[gn];
      #pragma unroll
      for (int reg = 0; reg < 4; ++reg) {
        size_t off = (size_t)(gm + reg) * 2048 + gn;
        float x = acc[tm][tn][reg] + cvv;
        if (mode) x += Abuf[off];
        else      Abuf[off] = x;
        acc[tm][tn][reg] = x;
      }
    }
  }

  // gate epilogue: two phases of 64 rows via LDS transpose
  float* zs = (float*)arena;
  int rl = t >> 2, j0 = (t & 3) * 8;
  #pragma unroll
  for (int ph = 0; ph < 2; ++ph) {
    __syncthreads();
    if ((wid >> 1) == ph) {
      #pragma unroll
      for (int tm = 0; tm < 4; ++tm)
        #pragma unroll
        for (int tn = 0; tn < 4; ++tn) {
          int rloc = tm*16 + q*4;
          int col = wn + tn*16 + fr;
          #pragma unroll
          for (int reg = 0; reg < 4; ++reg)
            zs[(rloc+reg)*132 + col] = acc[tm][tn][reg];
        }
    }
    __syncthreads();
    int gm_r = m0 + ph*64 + rl;
    #pragma unroll
    for (int e = 0; e < 8; ++e) {
      int jl = j0 + e;
      float zi = zs[rl*132 + jl];
      float zf = zs[rl*132 + 32 + jl];
      float zg = zs[rl*132 + 64 + jl];
      float zo = zs[rl*132 + 96 + jl];
      int jj = bx*32 + jl;
      float cold = mode ? cstate[(size_t)gm_r*512 + jj] : 0.f;
      float c2 = sigm(zf) * cold + sigm(zi) * tanhf(zg);
      if (mode != 2) cstate[(size_t)gm_r*512 + jj] = c2;
      if (bx < 8) {
        float h = qg[(size_t)gm_r*256 + jj] + sigm(zo) * tanhf(c2);
        if (mode == 2) hOut[(size_t)gm_r*256 + jj] = h;
        else           AhOut[(size_t)gm_r*256 + jj] = f2h(h);
      }
    }
  }
}

// ---------------------------------------------------------------- final cosine from hbuf
__global__ __launch_bounds__(256) void cos_kernel(
    const float* __restrict__ hbuf, const float* __restrict__ sgh, float* __restrict__ out) {
  int wid = threadIdx.x >> 6, lane = threadIdx.x & 63;
  int r = blockIdx.x*4 + wid;
  const float* hr = hbuf + (size_t)r*256;
  float d = 0.f, n2 = 0.f;
  #pragma unroll
  for (int i = 0; i < 4; ++i) {
    float v = hr[lane + i*64];
    d += v * sgh[lane + i*64];
    n2 += v * v;
  }
  #pragma unroll
  for (int off = 32; off; off >>= 1) { d += __shfl_down(d, off); n2 += __shfl_down(n2, off); }
  if (lane == 0) out[r] = d / fmaxf(sqrtf(n2), 1e-12f);
}

// ---------------------------------------------------------------- launch
extern "C" void kernel_launch(void* const* d_in, const int* in_sizes, int n_in,
                              void* d_out, int out_size, void* d_ws, size_t ws_size,
                              hipStream_t stream) {
  const float* emb   = (const float*)d_in[0];
  const float* gcnW  = (const float*)d_in[1];
  const float* gcnb  = (const float*)d_in[2];
  const float* gateW = (const float*)d_in[3];
  const float* gateb = (const float*)d_in[4];
  const float* sew1  = (const float*)d_in[5];
  const float* seb1  = (const float*)d_in[6];
  const float* sew2  = (const float*)d_in[7];
  const float* seb2  = (const float*)d_in[8];
  const float* lng   = (const float*)d_in[9];
  const float* lnb   = (const float*)d_in[10];
  const float* Wih   = (const float*)d_in[11];
  const float* Whh   = (const float*)d_in[12];
  const float* bih   = (const float*)d_in[13];
  const float* bhh   = (const float*)d_in[14];
  const int* query   = (const int*)d_in[15];
  const int* support = (const int*)d_in[16];
  const int* qlc     = (const int*)d_in[17];
  const int* qrc     = (const int*)d_in[19];
  const int* slc     = (const int*)d_in[21];
  const int* src     = (const int*)d_in[23];
  const int* knn     = (const int*)d_in[25];
  float* out = (float*)d_out;

  float* w = (float*)d_ws;
  size_t o = 0;
  auto alloc = [&](size_t n) { float* p = w + o; o += (n + 15) & ~(size_t)15; return p; };
  float* xbuf      = alloc((size_t)2056*256);
  float* query_g   = alloc((size_t)2056*256);
  float* sg_hat    = alloc(256);
  float* z_supp    = alloc(2048);
  float* cbuf      = alloc((size_t)2048*512);
  float* Abuf      = alloc((size_t)2048*2048);   // permuted columns
  float* hbuf      = alloc((size_t)2048*256);
  float* w1t       = alloc(256*512);
  float* w2t       = alloc(512*256);
  float* bias_p    = alloc(2048);
  ushort_t* AhA    = (ushort_t*)alloc((size_t)2048*128);   // 2048x256 fp16 bits
  ushort_t* AhB    = (ushort_t*)alloc((size_t)2048*128);
  ushort_t* Bih    = (ushort_t*)alloc((size_t)2048*128);   // permuted, 2048x256
  ushort_t* Bhh    = (ushort_t*)alloc((size_t)2048*128);
  (void)ws_size; (void)in_sizes; (void)n_in; (void)out_size;

  // 1) enc (blocks 0..4105) + all weight prep (blocks 4106..9233)
  encprep_kernel<<<9234, 256, 0, stream>>>(emb, gcnW, gcnb, gateW, gateb, knn,
                                           query, support, qlc, qrc, slc, src, xbuf,
                                           sew1, sew2, Wih, Whh, bih, bhh,
                                           w1t, w2t, Bih, Bhh, bias_p);

  // 2) MLP+LN on 2056 rows, emits fp16 A for rows<2048
  qenc_kernel<<<257, 256, 0, stream>>>(xbuf, w1t, seb1, w2t, seb2, lng, lnb, query_g, AhA);

  // 3) step 0: z = qg@Wih^T + bias (writes Abuf), gate epilogue (c_old=0) -> c, AhB;
  //    bx==16 stripe: finalize (sg_hat + z_supp)
  gemmgate_kernel<<<dim3(17,16), 256, 0, stream>>>(AhA, Bih, Abuf, bias_p,
                                                   query_g, cbuf, AhB, nullptr,
                                                   Whh, sg_hat, z_supp, 0);
  // 4) steps 1,2: z = h@Whh'^T + Abuf + z_supp, gate epilogue -> c, Ah (ping-pong)
  gemmgate_kernel<<<dim3(16,16), 256, 0, stream>>>(AhB, Bhh, Abuf, z_supp,
                                                   query_g, cbuf, AhA, nullptr,
                                                   Whh, sg_hat, z_supp, 1);
  gemmgate_kernel<<<dim3(16,16), 256, 0, stream>>>(AhA, Bhh, Abuf, z_supp,
                                                   query_g, cbuf, AhB, nullptr,
                                                   Whh, sg_hat, z_supp, 1);
  // 5) step 3 (final): only h-producing tiles (bx<8), write hbuf fp32
  gemmgate_kernel<<<dim3(8,16), 256, 0, stream>>>(AhB, Bhh, Abuf, z_supp,
                                                  query_g, cbuf, nullptr, hbuf,
                                                  Whh, sg_hat, z_supp, 2);
  // 6) cosine
  cos_kernel<<<512, 256, 0, stream>>>(hbuf, sg_hat, out);
}